// Round 11
// baseline (1610.750 us; speedup 1.0000x reference)
//
#include <hip/hip_runtime.h>
#include <hip/hip_bf16.h>

#define NPG 26
#define EPG 52
#define HDIM 128
#define NC 7
#define NFEAT 9
#define NVOC 119
#define AB_W 136

// ws layout (bytes)
#define ACC_OFF   0      // 2 x f32 accumulators
#define FLAG_OFF  8      // int dtype flag
#define BNSC_OFF  64     // f32[512]
#define BNSHB_OFF 2112   // f32[512]
#define ABL_OFF   4160   // f32[16]
#define LINW_OFF  4224   // f32[128]
#define LINB_OFF  4736   // f32[1]
#define AWT_OFF   4800   // u16[16*256]  (8 KB)
#define WT_OFF    13056  // u16[4*32768] (256 KB)  wt[li][c][ks][l4][j][kk8]

typedef unsigned int u32;
typedef unsigned short u16;
typedef float f32x4 __attribute__((ext_vector_type(4)));
typedef short short8 __attribute__((ext_vector_type(8)));

__device__ inline float b2f(u16 u){ union{u32 x; float f;} c; c.x = ((u32)u)<<16; return c.f; }
__device__ inline u16 f2b(float v){ union{ __hip_bfloat16 h; u16 u;} c; c.h = __float2bfloat16(v); return c.u; }
__device__ inline float ldp(const void* p, long long i, int bf){
  return bf ? b2f(((const u16*)p)[i]) : ((const float*)p)[i];
}
__device__ inline f32x4 mfma16(short8 a, short8 b, f32x4 c){
  return __builtin_amdgcn_mfma_f32_16x16x32_bf16(a, b, c, 0, 0, 0);
}
__device__ inline u32 pk2(float a, float b){ return (u32)f2b(a) | ((u32)f2b(b) << 16); }

__global__ void probe_dtype(const void* w, int* flag) {
  if (threadIdx.x == 0 && blockIdx.x == 0) {
    const u32* p = (const u32*)w;
    int big = 0;
    for (int i = 0; i < 256; ++i) {
      union { u32 x; float f; } c; c.x = (p[i] & 0xffffu) << 16;
      float v = fabsf(c.f);
      if (!(v < 1.0f)) big++;
    }
    *flag = (big < 16) ? 1 : 0;
  }
}

// wt[li][c][ks][l4][j][kk8]: quarter-wave-coalesced B fragments.
// flat o: kk8=o&7, j=(o>>3)&127, l4=(o>>10)&3, ks=(o>>12)&1, c=(o>>13)&3, li=o>>15
__global__ __launch_bounds__(256) void diffpool_prep(
    const void* convWl, const void* convbl, const void* convWr,
    const void* bng, const void* bnb, const void* bnrm, const void* bnrv,
    const void* aWl, const void* abl, const void* aWr,
    const void* linW, const void* linb, char* ws)
{
  const int bf = *(const int*)(ws + FLAG_OFF);
  u16* wt    = (u16*)(ws + WT_OFF);
  u16* awt   = (u16*)(ws + AWT_OFF);
  float* bnsc  = (float*)(ws + BNSC_OFF);
  float* bnshb = (float*)(ws + BNSHB_OFF);
  float* ablf  = (float*)(ws + ABL_OFF);
  float* linWf = (float*)(ws + LINW_OFF);
  float* linbf = (float*)(ws + LINB_OFF);
  const int t = blockIdx.x * 256 + threadIdx.x;
  const long long NT = (long long)gridDim.x * 256;
  for (long long o = t; o < 4LL*32768; o += NT) {
    int kk8 = (int)(o & 7);
    int j   = (int)((o >> 3) & 127);
    int l4  = (int)((o >> 10) & 3);
    int ks  = (int)((o >> 12) & 1);
    int c   = (int)((o >> 13) & 3);
    int li  = (int)(o >> 15);
    int k = c*64 + ks*32 + l4*8 + kk8;
    float v = (k < 128) ? ldp(convWl, (long long)li*16384 + (long long)k*128 + j, bf)
                        : ldp(convWr, (long long)li*16384 + (long long)(k-128)*128 + j, bf);
    wt[o] = f2b(v);
  }
  if (t < 4096) {
    int c = t >> 8, k = t & 255;
    float v = 0.f;
    if (c < NC) v = (k < 128) ? ldp(aWl, (long long)k*NC + c, bf)
                              : ldp(aWr, (long long)(k-128)*NC + c, bf);
    awt[t] = f2b(v);
  }
  if (t < 512) {
    float gg = ldp(bng, t, bf), b = ldp(bnb, t, bf);
    float rm = ldp(bnrm, t, bf), rv = ldp(bnrv, t, bf);
    float bl = ldp(convbl, t, bf);
    float sc = gg * rsqrtf(rv + 1e-5f);
    bnsc[t] = sc; bnshb[t] = b - rm*sc + bl*sc;
  }
  if (t < 128) linWf[t] = ldp(linW, t, bf);
  if (t < 16)  ablf[t] = (t < NC) ? ldp(abl, t, bf) : 0.f;
  if (t == 0)  linbf[0] = ldp(linb, 0, bf);
}

// on-the-fly neighbor-mean A-fragment: 8 channels [koff, koff+8) of row r
__device__ inline short8 meanfrag_row(const u16 (*ab)[AB_W], const int* cstart,
                                      const int* celist, const float* rdeg,
                                      int r, int koff) {
  short8 z = {0,0,0,0,0,0,0,0};
  if (r >= NPG) return z;
  float s0=0,s1=0,s2=0,s3=0,s4=0,s5=0,s6=0,s7=0;
  const int st = cstart[r], en = cstart[r+1];
  for (int e = st; e < en; ++e) {
    short8 hv = *(const short8*)&ab[celist[e]][koff];
    s0 += b2f((u16)hv[0]); s1 += b2f((u16)hv[1]);
    s2 += b2f((u16)hv[2]); s3 += b2f((u16)hv[3]);
    s4 += b2f((u16)hv[4]); s5 += b2f((u16)hv[5]);
    s6 += b2f((u16)hv[6]); s7 += b2f((u16)hv[7]);
  }
  const float rd = rdeg[r];
  short8 r8;
  r8[0]=(short)f2b(s0*rd); r8[1]=(short)f2b(s1*rd);
  r8[2]=(short)f2b(s2*rd); r8[3]=(short)f2b(s3*rd);
  r8[4]=(short)f2b(s4*rd); r8[5]=(short)f2b(s5*rd);
  r8[6]=(short)f2b(s6*rd); r8[7]=(short)f2b(s7*rd);
  return r8;
}

__global__ __launch_bounds__(256, 6) void diffpool_main(
    const int* __restrict__ xfeat,
    const int* __restrict__ esrc,
    const int* __restrict__ edst,
    const void* __restrict__ emb,
    void* __restrict__ out,
    char* __restrict__ ws)
{
  const int bfflag = *(const int*)(ws + FLAG_OFF);
  const u16* wt    = (const u16*)(ws + WT_OFF);
  const u16* awt   = (const u16*)(ws + AWT_OFF);
  const float* bnsc  = (const float*)(ws + BNSC_OFF);
  const float* bnshb = (const float*)(ws + BNSHB_OFF);
  const float* ablf  = (const float*)(ws + ABL_OFF);
  const float* linWf = (const float*)(ws + LINW_OFF);
  const float* linbf = (const float*)(ws + LINB_OFF);
  float* accum = (float*)(ws + ACC_OFF);

  // ~11.6 KB LDS
  __shared__ alignas(16) u16 ab[32][AB_W];   // h; later rows 0-6 = x2, row 8 = m
  __shared__ alignas(16) u16 sdT[16][32];
  __shared__ float sd_s[NPG][8];
  __shared__ float redg[4];
  __shared__ int lsrc[EPG], ldst[EPG], celist[EPG];
  __shared__ int cstart[NPG + 1], ccnt[NPG];
  __shared__ float rdeg[NPG];

  const int tid  = threadIdx.x;
  const int g    = blockIdx.x;
  const int gw   = tid >> 6;
  const int lane = tid & 63;
  const int l4   = lane >> 4;
  const int lm   = lane & 15;
  const int jc0  = gw*32 + lm, jc1 = jc0 + 16;

  // ---------- phase 0: wave0 = CSR (wave-lockstep, no barriers); waves 1-3 = encoder + zeroing ----------
  if (gw == 0) {
    if (lane < NPG) ccnt[lane] = 0;
    int ls = 0, ld = 0;
    const bool ed = lane < EPG;
    if (ed) {
      ls = esrc[(long long)g*EPG + lane] - g*NPG;
      ld = edst[(long long)g*EPG + lane] - g*NPG;
      lsrc[lane] = ls; ldst[lane] = ld;
      atomicAdd(&ccnt[ld], 1);
    }
    int c = (lane < NPG) ? ccnt[lane] : 0;
    int sc = c;
    #pragma unroll
    for (int off = 1; off <= 16; off <<= 1) {
      int o = __shfl_up(sc, off);
      if ((lane & 31) >= off) sc += o;
    }
    if (lane < NPG) { cstart[lane + 1] = sc; rdeg[lane] = 1.f / fmaxf((float)c, 1.f); }
    if (lane == 0) cstart[0] = 0;
    if (lane < NPG) ccnt[lane] = 0;
    if (ed) { int pos = cstart[ld] + atomicAdd(&ccnt[ld], 1); celist[pos] = ls; }
  } else {
    const int lt = (gw - 1)*64 + lane;           // 0..191
    for (int i = lt; i < 256; i += 192) ((u32*)sdT)[i] = 0;
    for (int i = lt; i < 2048; i += 192) {       // 32 rows x 64 ch-pairs (rows>=26 zero pad)
      int n = i >> 6, jp = i & 63;
      u32 val = 0;
      if (n < NPG) {
        const int* xfp = xfeat + (long long)g*NPG*NFEAT + n*NFEAT;
        float a0 = 0.f, a1 = 0.f;
        if (bfflag) {
          #pragma unroll
          for (int f = 0; f < NFEAT; ++f) {
            u32 ev = *(const u32*)((const u16*)emb + ((long long)(f*NVOC + xfp[f])*HDIM + 2*jp));
            a0 += b2f((u16)ev); a1 += b2f((u16)(ev >> 16));
          }
        } else {
          #pragma unroll
          for (int f = 0; f < NFEAT; ++f) {
            float2 ev = ((const float2*)emb)[(long long)(f*NVOC + xfp[f])*64 + jp];
            a0 += ev.x; a1 += ev.y;
          }
        }
        val = pk2(a0, a1);
      }
      *(u32*)&ab[n][2*jp] = val;
    }
  }
  __syncthreads();

  // ---------- 2 SAGE layers: barrier-free GEMM ----------
  for (int li = 0; li < 2; ++li) {
    f32x4 a00 = {0,0,0,0}, a01 = {0,0,0,0}, a10 = {0,0,0,0}, a11 = {0,0,0,0};
    const u16* wb = wt + (size_t)li*32768 + (size_t)l4*1024 + (size_t)jc0*8;
    #pragma unroll
    for (int c = 0; c < 4; ++c) {
      #pragma unroll
      for (int ks = 0; ks < 2; ++ks) {
        const u16* bp = wb + c*8192 + ks*4096;
        short8 b0 = *(const short8*)(bp);
        short8 b1 = *(const short8*)(bp + 128);   // jc1 = jc0+16 -> +16*8
        const int koff = c*64 + ks*32 + 8*l4;
        short8 af0, af1;
        if (c < 2) {
          af0 = meanfrag_row(ab, cstart, celist, rdeg, lm, koff);
          af1 = meanfrag_row(ab, cstart, celist, rdeg, 16 + lm, koff);
        } else {
          af0 = *(const short8*)&ab[lm][koff - 128];
          af1 = *(const short8*)&ab[16 + lm][koff - 128];
        }
        a00 = mfma16(af0, b0, a00); a01 = mfma16(af0, b1, a01);
        a10 = mfma16(af1, b0, a10); a11 = mfma16(af1, b1, a11);
      }
    }
    __syncthreads();   // all A reads (mean + h) done before h writes

    const float sc0 = bnsc[li*128 + jc0], sb0 = bnshb[li*128 + jc0];
    const float sc1 = bnsc[li*128 + jc1], sb1 = bnshb[li*128 + jc1];
    #pragma unroll
    for (int rr = 0; rr < 4; ++rr) {
      int n = 4*l4 + rr;
      float v0 = fmaxf(fmaf(a00[rr], sc0, sb0), 0.f);
      float v1 = fmaxf(fmaf(a01[rr], sc1, sb1), 0.f);
      ab[n][jc0] = f2b(v0 + b2f(ab[n][jc0]));
      ab[n][jc1] = f2b(v1 + b2f(ab[n][jc1]));
      int n1 = 16 + 4*l4 + rr;
      if (n1 < NPG) {
        float u0 = fmaxf(fmaf(a10[rr], sc0, sb0), 0.f);
        float u1 = fmaxf(fmaf(a11[rr], sc1, sb1), 0.f);
        ab[n1][jc0] = f2b(u0 + b2f(ab[n1][jc0]));
        ab[n1][jc1] = f2b(u1 + b2f(ab[n1][jc1]));
      }
    }
    __syncthreads();
  }

  // ---------- assignment conv (waves 0-1, barrier-free) ----------
  if (gw < 2) {
    const u16* ar = awt + (lm << 8) + 8*l4;
    f32x4 acc = {0,0,0,0};
    #pragma unroll
    for (int c = 0; c < 8; ++c) {
      short8 bv = *(const short8*)(ar + c*32);
      const int koff = c*32 + 8*l4;
      short8 af = (c < 4) ? meanfrag_row(ab, cstart, celist, rdeg, gw*16 + lm, koff)
                          : *(const short8*)&ab[gw*16 + lm][koff - 128];
      acc = mfma16(af, bv, acc);
    }
    float bl = ablf[lm];
    #pragma unroll
    for (int rr = 0; rr < 4; ++rr) {
      int n = gw*16 + 4*l4 + rr;
      if (n < NPG && lm < NC) sd_s[n][lm] = acc[rr] + bl;
    }
  }
  __syncthreads();

  // ---------- softmax + entropy ----------
  {
    float ent = 0.f;
    if (tid < NPG) {
      float mx = sd_s[tid][0];
      #pragma unroll
      for (int c = 1; c < NC; ++c) mx = fmaxf(mx, sd_s[tid][c]);
      float ex[NC], se = 0.f, dot = 0.f;
      #pragma unroll
      for (int c = 0; c < NC; ++c) {
        float d = sd_s[tid][c] - mx;
        ex[c] = expf(d); se += ex[c]; dot = fmaf(ex[c], d, dot);
      }
      float inv = 1.f / se;
      #pragma unroll
      for (int c = 0; c < NC; ++c) sd_s[tid][c] = ex[c]*inv;
      ent = logf(se) - dot*inv;
    }
    if (gw == 0) {
      float v = ent;
      #pragma unroll
      for (int off = 32; off >= 1; off >>= 1) v += __shfl_down(v, off);
      if (lane == 0) atomicAdd(&accum[1], v);
    }
  }
  __syncthreads();
  if (tid < NPG*NC) { int n = tid/7, c = tid%7; sdT[c][n] = f2b(sd_s[n][c]); }

  // ---------- link loss: sum_e mult(e) - 2*sum_e ss_e + ||S^T S||_F^2 ----------
  {
    float lv = 0.f;
    if (tid < EPG) {
      int key = lsrc[tid]*32 + ldst[tid];
      int cnt = 0;
      for (int e = 0; e < EPG; ++e) cnt += ((lsrc[e]*32 + ldst[e]) == key) ? 1 : 0;
      float ss = 0.f;
      #pragma unroll
      for (int c = 0; c < NC; ++c) ss = fmaf(sd_s[lsrc[tid]][c], sd_s[ldst[tid]][c], ss);
      lv = (float)cnt - 2.f*ss;
    } else if (tid >= 64 && tid < 64 + NC*NC) {
      int idx = tid - 64, c1 = idx/7, c2 = idx%7;
      float m = 0.f;
      for (int n = 0; n < NPG; ++n) m = fmaf(sd_s[n][c1], sd_s[n][c2], m);
      lv = m*m;
    }
    #pragma unroll
    for (int off = 32; off >= 1; off >>= 1) lv += __shfl_down(lv, off);
    if (lane == 0) redg[gw] = lv;
  }
  __syncthreads();              // redg + sdT published
  if (tid == 0) atomicAdd(&accum[0], redg[0] + redg[1] + redg[2] + redg[3]);

  // ---------- x2 = S^T h ----------
  f32x4 e0 = {0,0,0,0}, e1 = {0,0,0,0};
  {
    short8 af = *(const short8*)&sdT[lm][8*l4];
    short8 b0, b1;
    #pragma unroll
    for (int i = 0; i < 8; ++i) {
      int n = 8*l4 + i;
      b0[i] = (short)ab[n][jc0]; b1[i] = (short)ab[n][jc1];
    }
    e0 = mfma16(af, b0, e0); e1 = mfma16(af, b1, e1);
  }
  __syncthreads();              // all h reads done
  #pragma unroll
  for (int rr = 0; rr < 4; ++rr) {
    int cc = 4*l4 + rr;
    if (cc < NC) { ab[cc][jc0] = f2b(e0[rr]); ab[cc][jc1] = f2b(e1[rr]); }
  }
  __syncthreads();

  // ---------- pooled dense layers (barrier-free GEMM, broadcast m in ab[8]) ----------
  for (int li = 2; li < 4; ++li) {
    if (tid < 64) {
      int jp = tid; float s0 = 0.f, s1 = 0.f;
      #pragma unroll
      for (int c = 0; c < NC; ++c) {
        u32 v = *(const u32*)&ab[c][2*jp];
        s0 += b2f((u16)v); s1 += b2f((u16)(v >> 16));
      }
      *(u32*)&ab[8][2*jp] = pk2(s0*(1.f/7.f), s1*(1.f/7.f));
    }
    __syncthreads();
    f32x4 a0 = {0,0,0,0}, a1 = {0,0,0,0};
    const u16* wb = wt + (size_t)li*32768 + (size_t)l4*1024 + (size_t)jc0*8;
    #pragma unroll
    for (int c = 0; c < 4; ++c) {
      #pragma unroll
      for (int ks = 0; ks < 2; ++ks) {
        const u16* bp = wb + c*8192 + ks*4096;
        short8 b0 = *(const short8*)(bp);
        short8 b1 = *(const short8*)(bp + 128);
        const int koff = c*64 + ks*32 + 8*l4;
        short8 af = (c < 2) ? *(const short8*)&ab[8][koff]        // broadcast m
                            : *(const short8*)&ab[lm][koff - 128]; // x2 rows (7-15 garbage, discarded)
        a0 = mfma16(af, b0, a0); a1 = mfma16(af, b1, a1);
      }
    }
    __syncthreads();            // x2 reads done before overwrite
    const float sc0 = bnsc[li*128 + jc0], sb0 = bnshb[li*128 + jc0];
    const float sc1 = bnsc[li*128 + jc1], sb1 = bnshb[li*128 + jc1];
    #pragma unroll
    for (int rr = 0; rr < 4; ++rr) {
      int cc = 4*l4 + rr;
      if (cc < NC) {
        float v0 = fmaf(a0[rr], sc0, sb0) + b2f(ab[cc][jc0]);
        float v1 = fmaf(a1[rr], sc1, sb1) + b2f(ab[cc][jc1]);
        ab[cc][jc0] = f2b(v0);
        ab[cc][jc1] = f2b(v1);
      }
    }
    __syncthreads();
  }

  // ---------- readout ----------
  if (tid < 64) {
    int jp = tid; float s0 = 0.f, s1 = 0.f;
    #pragma unroll
    for (int c = 0; c < NC; ++c) {
      u32 v = *(const u32*)&ab[c][2*jp];
      s0 += b2f((u16)v); s1 += b2f((u16)(v >> 16));
    }
    float v = (s0*(1.f/7.f))*linWf[2*jp] + (s1*(1.f/7.f))*linWf[2*jp+1];
    #pragma unroll
    for (int off = 32; off >= 1; off >>= 1) v += __shfl_down(v, off);
    if (tid == 0) {
      float z = v + linbf[0];
      float o = 1.f / (1.f + expf(-z));
      if (bfflag) ((u16*)out)[g] = f2b(o); else ((float*)out)[g] = o;
    }
  }
}

__global__ void diffpool_finalize(const char* __restrict__ ws, void* __restrict__ out, int nb) {
  if (threadIdx.x == 0 && blockIdx.x == 0) {
    const float* accum = (const float*)(ws + ACC_OFF);
    const int bf = *(const int*)(ws + FLAG_OFF);
    float link = sqrtf(fmaxf(accum[0], 0.f)) / ((float)nb * (float)(NPG*NPG));
    float ent  = accum[1] / ((float)nb * (float)NPG);
    if (bf) { ((u16*)out)[nb] = f2b(link); ((u16*)out)[nb+1] = f2b(ent); }
    else    { ((float*)out)[nb] = link;    ((float*)out)[nb+1] = ent; }
  }
}

extern "C" void kernel_launch(void* const* d_in, const int* in_sizes, int n_in,
                              void* d_out, int out_size, void* d_ws, size_t ws_size,
                              hipStream_t stream) {
  const int* x  = (const int*)d_in[0];
  const int* ei = (const int*)d_in[1];
  const int ntot = in_sizes[0] / NFEAT;
  const int nb   = ntot / NPG;
  const int* esrc = ei;
  const int* edst = ei + (long long)nb * EPG;
  char* ws = (char*)d_ws;
  int* flag = (int*)(ws + FLAG_OFF);

  hipMemsetAsync(ws, 0, 16, stream);
  probe_dtype<<<1, 64, 0, stream>>>(d_in[4], flag);
  diffpool_prep<<<256, 256, 0, stream>>>(
      d_in[4], d_in[5], d_in[6],
      d_in[7], d_in[8], d_in[9], d_in[10],
      d_in[11], d_in[12], d_in[13], d_in[14], d_in[15], ws);
  diffpool_main<<<nb, 256, 0, stream>>>(x, esrc, edst, d_in[3], d_out, ws);
  diffpool_finalize<<<1, 64, 0, stream>>>(ws, d_out, nb);
}